// Round 16
// baseline (32.792 us; speedup 1.0000x reference)
//
#include <hip/hip_runtime.h>

// GrowingSignature: truncated iterated-sums signature, levels 1..4, F=4.
// x: (32, 512, 4) f32;  out: (32, 512, 341) f32.
// R16: iso-depth workgroup reduction. Evidence fit across R3-R15: dur ~=
// fixed + ~6-8ns/workgroup; inner-loop content neutral. So: 128 blocks per
// kernel (was 512), each handling 4 STRIDED chunks {g,g+4,g+8,g+12} as 4
// independent interleaved chains -> serial depth unchanged (32 scan steps,
// 15 combine rows), wg count 1024 -> 256.
// Word layout (signatory order): len1 cols 1..4, len2 cols 5..20,
// len3 cols 21..84, len4 cols 85..340; word (a,b,c,e) -> 85+64a+16b+4c+e.

#define SIG_B 32
#define SIG_L 512
#define SIG_NSTEP 511
#define SIG_ROW 341
#define SIG_CS 32            // chunk size (increments)
#define SIG_C 16             // chunks per batch
#define SIG_G 4              // blocks per batch (each owns 4 strided chunks)
#define SIG_PAD 344          // workspace row stride (floats, %4==0)

// Stage increments of the block's 4 strided chunks: dlds[k][t][f].
// Chunk ck = g + 4k; global step gt = ck*32 + t; gt==511 is zero-padded.
__device__ __forceinline__ void stage4(const float* __restrict__ xb,
                                       float* dlds, int tid, int g) {
    if (tid < 128) {
        const int k = tid >> 5, t = tid & 31;
        const int gt = (g + 4 * k) * SIG_CS + t;
        float4 d = make_float4(0.f, 0.f, 0.f, 0.f);
        if (gt < SIG_NSTEP) {
            float4 x0 = *(const float4*)(xb + gt * 4);
            float4 x1 = *(const float4*)(xb + gt * 4 + 4);
            d = make_float4(x1.x - x0.x, x1.y - x0.y, x1.z - x0.z, x1.w - x0.w);
        }
        *(float4*)(dlds + (k * SIG_CS + t) * 4) = d;
    }
}

#define SIG_CHAIN_STEP(K, S1, S2, S3, S4)                                   \
    do {                                                                    \
        const float* dp_ = dlds + ((K) * SIG_CS + t) * 4;                   \
        const float da_ = dp_[a], db_ = dp_[bb], dc_ = dp_[cc], de_ = dp_[ee];\
        S4 = fmaf(S3, de_, S4);   /* top level first: pre-update lower */   \
        S3 = fmaf(S2, dc_, S3);                                             \
        S2 = fmaf(S1, db_, S2);                                             \
        S1 += da_;                                                          \
    } while (0)

// ---------- Kernel A: 4 chunk-local signatures per block ----------
__global__ __launch_bounds__(256) void sigA4(const float* __restrict__ x,
                                             float* __restrict__ Lsig) {
    const int b = blockIdx.x >> 2, g = blockIdx.x & 3;
    const int tid = threadIdx.x;

    __shared__ float dlds[SIG_G * SIG_CS * 4];
    stage4(x + (size_t)b * SIG_L * 4, dlds, tid, g);
    __syncthreads();

    const int a = tid >> 6, bb = (tid >> 4) & 3, cc = (tid >> 2) & 3, ee = tid & 3;

    float s1_0 = 0.f, s2_0 = 0.f, s3_0 = 0.f, s4_0 = 0.f;
    float s1_1 = 0.f, s2_1 = 0.f, s3_1 = 0.f, s4_1 = 0.f;
    float s1_2 = 0.f, s2_2 = 0.f, s3_2 = 0.f, s4_2 = 0.f;
    float s1_3 = 0.f, s2_3 = 0.f, s3_3 = 0.f, s4_3 = 0.f;

#pragma unroll 4
    for (int t = 0; t < SIG_CS; ++t) {   // depth 32; 4 independent chains (ILP)
        SIG_CHAIN_STEP(0, s1_0, s2_0, s3_0, s4_0);
        SIG_CHAIN_STEP(1, s1_1, s2_1, s3_1, s4_1);
        SIG_CHAIN_STEP(2, s1_2, s2_2, s3_2, s4_2);
        SIG_CHAIN_STEP(3, s1_3, s2_3, s3_3, s4_3);
    }

#define SIG_WRITE_L(K, S1, S2, S3, S4)                                      \
    do {                                                                    \
        float* Lr = Lsig + (size_t)(b * SIG_C + g + 4 * (K)) * SIG_PAD;     \
        if ((tid & 63) == 0) Lr[1 + a] = S1;                                \
        if ((tid & 15) == 0) Lr[5 + (tid >> 4)] = S2;                       \
        if ((tid & 3) == 0)  Lr[21 + (tid >> 2)] = S3;                      \
        Lr[85 + tid] = S4;                                                  \
    } while (0)

    SIG_WRITE_L(0, s1_0, s2_0, s3_0, s4_0);
    SIG_WRITE_L(1, s1_1, s2_1, s3_1, s4_1);
    SIG_WRITE_L(2, s1_2, s2_2, s3_2, s4_2);
    SIG_WRITE_L(3, s1_3, s2_3, s3_3, s4_3);
#undef SIG_WRITE_L
}

// ---------- Kernel C: one combine pass w/ snapshots + 4 seeded scans ----------
__global__ __launch_bounds__(256) void sigC4(const float* __restrict__ x,
                                             const float* __restrict__ Lsig,
                                             float* __restrict__ out) {
    const int b = blockIdx.x >> 2, g = blockIdx.x & 3;
    const int tid = threadIdx.x;

    __shared__ float dlds[SIG_G * SIG_CS * 4];
    __shared__ float L[(SIG_C - 1) * SIG_PAD];   // rows 0..14

    stage4(x + (size_t)b * SIG_L * 4, dlds, tid, g);
    {
        const float4* Lb4 = (const float4*)(Lsig + (size_t)b * SIG_C * SIG_PAD);
        float4* L4p = (float4*)L;
        const int n4 = (SIG_C - 1) * (SIG_PAD / 4);
        for (int i = tid; i < n4; i += 256) L4p[i] = Lb4[i];
    }
    __syncthreads();

    const int a = tid >> 6, bb = (tid >> 4) & 3, cc = (tid >> 2) & 3, ee = tid & 3;
    const int c0 = g, c1 = g + 4, c2 = g + 8, c3 = g + 12;

    // One combine pass over rows 0..14; snapshot running prefix p at each
    // chain's chunk index (prefix of chunk ck = rows 0..ck-1 applied).
    float p1 = 0.f, p2 = 0.f, p3 = 0.f, p4 = 0.f;
    float q1_0, q2_0, q3_0, q4_0, q1_1, q2_1, q3_1, q4_1;
    float q1_2, q2_2, q3_2, q4_2, q1_3, q2_3, q3_3, q4_3;
    for (int j = 0; j < SIG_C - 1; ++j) {
        if (j == c0) { q1_0 = p1; q2_0 = p2; q3_0 = p3; q4_0 = p4; }
        if (j == c1) { q1_1 = p1; q2_1 = p2; q3_1 = p3; q4_1 = p4; }
        if (j == c2) { q1_2 = p1; q2_2 = p2; q3_2 = p3; q4_2 = p4; }
        if (j == c3) { q1_3 = p1; q2_3 = p2; q3_3 = p3; q4_3 = p4; }
        const float* Lc = L + j * SIG_PAD;
        const float l1a = Lc[1 + a], l1b = Lc[1 + bb], l1c = Lc[1 + cc], l1e = Lc[1 + ee];
        const float l2ab = Lc[5 + 4 * a + bb], l2bc = Lc[5 + 4 * bb + cc],
                    l2ce = Lc[5 + 4 * cc + ee];
        const float l3abc = Lc[21 + 16 * a + 4 * bb + cc],
                    l3bce = Lc[21 + 16 * bb + 4 * cc + ee];
        const float l4 = Lc[85 + tid];
        p4 += p3 * l1e + p2 * l2ce + p1 * l3bce + l4;  // uses pre-update p1..p3
        p3 += p2 * l1c + p1 * l2bc + l3abc;
        p2 += p1 * l1b + l2ab;
        p1 += l1a;
    }
    if (c3 == SIG_C - 1) { q1_3 = p1; q2_3 = p2; q3_3 = p3; q4_3 = p4; }

    if (g == 0) {  // row 0: [1, zeros]
        float* r0 = out + (size_t)b * SIG_L * SIG_ROW;
        if (tid == 0)        __builtin_nontemporal_store(1.0f, r0 + 0);
        if ((tid & 63) == 0) __builtin_nontemporal_store(0.f, r0 + 1 + a);
        if ((tid & 15) == 0) __builtin_nontemporal_store(0.f, r0 + 5 + (tid >> 4));
        if ((tid & 3) == 0)  __builtin_nontemporal_store(0.f, r0 + 21 + (tid >> 2));
        __builtin_nontemporal_store(0.f, r0 + 85 + tid);
    }

    float* row0p = out + ((size_t)b * SIG_L + c0 * SIG_CS + 1) * SIG_ROW;
    float* row1p = out + ((size_t)b * SIG_L + c1 * SIG_CS + 1) * SIG_ROW;
    float* row2p = out + ((size_t)b * SIG_L + c2 * SIG_CS + 1) * SIG_ROW;
    float* row3p = out + ((size_t)b * SIG_L + c3 * SIG_CS + 1) * SIG_ROW;
    const bool last3 = (c3 == SIG_C - 1);   // chunk 15 has only 31 real steps

#define SIG_STORE_ROW(RP, S1, S2, S3, S4)                                    \
    do {                                                                     \
        float* r_ = (RP) + (size_t)t * SIG_ROW;                              \
        if (tid == 0)        __builtin_nontemporal_store(1.0f, r_ + 0);      \
        if ((tid & 63) == 0) __builtin_nontemporal_store(S1, r_ + 1 + a);    \
        if ((tid & 15) == 0) __builtin_nontemporal_store(S2, r_ + 5 + (tid >> 4)); \
        if ((tid & 3) == 0)  __builtin_nontemporal_store(S3, r_ + 21 + (tid >> 2)); \
        __builtin_nontemporal_store(S4, r_ + 85 + tid);                      \
    } while (0)

#pragma unroll 4
    for (int t = 0; t < SIG_CS; ++t) {   // depth 32; 4 independent seeded scans
        SIG_CHAIN_STEP(0, q1_0, q2_0, q3_0, q4_0);
        SIG_CHAIN_STEP(1, q1_1, q2_1, q3_1, q4_1);
        SIG_CHAIN_STEP(2, q1_2, q2_2, q3_2, q4_2);
        SIG_CHAIN_STEP(3, q1_3, q2_3, q3_3, q4_3);
        SIG_STORE_ROW(row0p, q1_0, q2_0, q3_0, q4_0);
        SIG_STORE_ROW(row1p, q1_1, q2_1, q3_1, q4_1);
        SIG_STORE_ROW(row2p, q1_2, q2_2, q3_2, q4_2);
        if (!last3 || t < SIG_CS - 1)    // chunk 15: skip padded step 31
            SIG_STORE_ROW(row3p, q1_3, q2_3, q3_3, q4_3);
    }
#undef SIG_STORE_ROW
}

extern "C" void kernel_launch(void* const* d_in, const int* in_sizes, int n_in,
                              void* d_out, int out_size, void* d_ws, size_t ws_size,
                              hipStream_t stream) {
    const float* x = (const float*)d_in[0];   // (32, 512, 4) f32
    float* out = (float*)d_out;               // (32, 512, 341) f32
    float* Lsig = (float*)d_ws;               // 512 * 344 floats

    sigA4<<<SIG_B * SIG_G, 256, 0, stream>>>(x, Lsig);
    sigC4<<<SIG_B * SIG_G, 256, 0, stream>>>(x, Lsig, out);
}

// Round 17
// 20.586 us; speedup vs baseline: 1.5929x; 1.5929x over previous
//
#include <hip/hip_runtime.h>

// GrowingSignature: truncated iterated-sums signature, levels 1..4, F=4.
// x: (32, 512, 4) f32;  out: (32, 512, 341) f32.
// R8 anchor (2-kernel chunked scan, CS=32/C=16) + R17 change: sigC's scan
// batches stores 4 steps at a time from snapshot registers. Rationale: a
// VMEM store holds its source VGPRs until processed; storing p1..p4 and
// immediately overwriting them each step puts store latency (~300 cyc) on
// the serial chain (fits R2's 333 cyc/step; R16's 4x-stores regression;
// R15's read-side unroll neutrality). Snapshots decouple recursion from
// in-flight stores; hazard amortized 4x.
// Word layout (signatory order): len1 cols 1..4, len2 cols 5..20,
// len3 cols 21..84, len4 cols 85..340; word (a,b,c,e) -> 85+64a+16b+4c+e.

#define SIG_B 32
#define SIG_L 512
#define SIG_NSTEP 511
#define SIG_ROW 341
#define SIG_CS 32            // chunk size (increments)
#define SIG_C 16             // chunks per batch
#define SIG_PAD 344          // padded row stride in workspace (floats, %4==0)

// ---------- Kernel A: local chunk signatures (R8 body, unchanged) ----------
__global__ __launch_bounds__(256) void sigA(const float* __restrict__ x,
                                            float* __restrict__ Lsig) {
    const int bc = blockIdx.x;
    const int b = bc / SIG_C, c = bc % SIG_C;
    const int tid = threadIdx.x;
    const int t0 = c * SIG_CS;
    const int nt = min(SIG_CS, SIG_NSTEP - t0);   // 32, or 31 for last chunk

    __shared__ float dlds[SIG_CS * 4];
    const float* xb = x + ((size_t)b * SIG_L + t0) * 4;
    if (tid < nt) {
        float4 x0 = *(const float4*)(xb + tid * 4);
        float4 x1 = *(const float4*)(xb + (tid + 1) * 4);
        *(float4*)(dlds + tid * 4) =
            make_float4(x1.x - x0.x, x1.y - x0.y, x1.z - x0.z, x1.w - x0.w);
    }
    __syncthreads();

    const int a = tid >> 6, bb = (tid >> 4) & 3, cc = (tid >> 2) & 3, ee = tid & 3;
    float s1 = 0.f, s2 = 0.f, s3 = 0.f, s4 = 0.f;
    const float* dp = dlds;
    for (int t = 0; t < nt; ++t) {
        const float da = dp[a], db = dp[bb], dc = dp[cc], de = dp[ee];
        dp += 4;
        s4 = fmaf(s3, de, s4);  // top level first: consumes pre-update s3
        s3 = fmaf(s2, dc, s3);
        s2 = fmaf(s1, db, s2);
        s1 += da;
    }
    float* Lr = Lsig + (size_t)bc * SIG_PAD;
    if ((tid & 63) == 0) Lr[1 + a] = s1;
    if ((tid & 15) == 0) Lr[5 + (tid >> 4)] = s2;
    if ((tid & 3) == 0)  Lr[21 + (tid >> 2)] = s3;
    Lr[85 + tid] = s4;
}

// ---------- Kernel C: prefix combine + scan with 4-step store batching ----------
__global__ __launch_bounds__(256) void sigC(const float* __restrict__ x,
                                            const float* __restrict__ Lsig,
                                            float* __restrict__ out) {
    const int bc = blockIdx.x;
    const int b = bc / SIG_C, c = bc % SIG_C;
    const int tid = threadIdx.x;
    const int t0 = c * SIG_CS;
    const int nt = min(SIG_CS, SIG_NSTEP - t0);

    __shared__ float dlds[SIG_CS * 4];
    __shared__ float L[SIG_C * SIG_PAD];

    const float* xb = x + ((size_t)b * SIG_L + t0) * 4;
    if (tid < SIG_CS) {
        float4 d = make_float4(0.f, 0.f, 0.f, 0.f);   // zero-pad tail step
        if (tid < nt) {
            float4 x0 = *(const float4*)(xb + tid * 4);
            float4 x1 = *(const float4*)(xb + (tid + 1) * 4);
            d = make_float4(x1.x - x0.x, x1.y - x0.y, x1.z - x0.z, x1.w - x0.w);
        }
        *(float4*)(dlds + tid * 4) = d;
    }
    // Stage the c preceding chunk signatures (only what this block combines).
    {
        const float4* Lb4 = (const float4*)(Lsig + (size_t)b * SIG_C * SIG_PAD);
        float4* L4p = (float4*)L;
        const int n4 = c * (SIG_PAD / 4);
        for (int i = tid; i < n4; i += 256) L4p[i] = Lb4[i];
    }
    __syncthreads();

    const int a = tid >> 6, bb = (tid >> 4) & 3, cc = (tid >> 2) & 3, ee = tid & 3;

    // Chen-combine chunks 0..c-1 -> prefix (p1..p4) for this lane's word.
    float p1 = 0.f, p2 = 0.f, p3 = 0.f, p4 = 0.f;
    for (int j = 0; j < c; ++j) {
        const float* Lc = L + j * SIG_PAD;
        const float l1a = Lc[1 + a], l1b = Lc[1 + bb], l1c = Lc[1 + cc], l1e = Lc[1 + ee];
        const float l2ab = Lc[5 + 4 * a + bb], l2bc = Lc[5 + 4 * bb + cc],
                    l2ce = Lc[5 + 4 * cc + ee];
        const float l3abc = Lc[21 + 16 * a + 4 * bb + cc],
                    l3bce = Lc[21 + 16 * bb + 4 * cc + ee];
        const float l4 = Lc[85 + tid];
        p4 += p3 * l1e + p2 * l2ce + p1 * l3bce + l4;  // uses pre-update p1..p3
        p3 += p2 * l1c + p1 * l2bc + l3abc;
        p2 += p1 * l1b + l2ab;
        p1 += l1a;
    }

    float* row = out + ((size_t)b * SIG_L + (t0 + 1)) * SIG_ROW;

    if (c == 0) {  // row 0: [1, zeros]
        float* r0 = out + (size_t)b * SIG_L * SIG_ROW;
        if (tid == 0)        __builtin_nontemporal_store(1.0f, r0 + 0);
        if ((tid & 63) == 0) __builtin_nontemporal_store(0.f, r0 + 1 + a);
        if ((tid & 15) == 0) __builtin_nontemporal_store(0.f, r0 + 5 + (tid >> 4));
        if ((tid & 3) == 0)  __builtin_nontemporal_store(0.f, r0 + 21 + (tid >> 2));
        __builtin_nontemporal_store(0.f, r0 + 85 + tid);
    }

    // Scan with 4-step store batching: recursion runs 4 steps into snapshot
    // regs (static indices -> renamed, no scratch), then 4 rows of stores.
    // Recursion registers are never sources of in-flight stores; snapshot
    // regs are rewritten a full batch later (4x store slack).
    for (int tb = 0; tb < SIG_CS; tb += 4) {
        float o1_0, o2_0, o3_0, o4_0, o1_1, o2_1, o3_1, o4_1;
        float o1_2, o2_2, o3_2, o4_2, o1_3, o2_3, o3_3, o4_3;
#define SIG_STEP_SNAP(U, O1, O2, O3, O4)                                     \
        do {                                                                 \
            const float* dp_ = dlds + (tb + (U)) * 4;                        \
            const float da_ = dp_[a], db_ = dp_[bb],                         \
                        dc_ = dp_[cc], de_ = dp_[ee];                        \
            p4 = fmaf(p3, de_, p4);  /* pre-update lower levels */           \
            p3 = fmaf(p2, dc_, p3);                                          \
            p2 = fmaf(p1, db_, p2);                                          \
            p1 += da_;                                                       \
            O1 = p1; O2 = p2; O3 = p3; O4 = p4;                              \
        } while (0)
        SIG_STEP_SNAP(0, o1_0, o2_0, o3_0, o4_0);
        SIG_STEP_SNAP(1, o1_1, o2_1, o3_1, o4_1);
        SIG_STEP_SNAP(2, o1_2, o2_2, o3_2, o4_2);
        SIG_STEP_SNAP(3, o1_3, o2_3, o3_3, o4_3);
#undef SIG_STEP_SNAP

#define SIG_STORE_ROW(U, O1, O2, O3, O4)                                     \
        do {                                                                 \
            if (tb + (U) < nt) {                                             \
                float* r_ = row + (size_t)(tb + (U)) * SIG_ROW;              \
                if (tid == 0)                                                \
                    __builtin_nontemporal_store(1.0f, r_ + 0);               \
                if ((tid & 63) == 0)                                         \
                    __builtin_nontemporal_store(O1, r_ + 1 + a);             \
                if ((tid & 15) == 0)                                         \
                    __builtin_nontemporal_store(O2, r_ + 5 + (tid >> 4));    \
                if ((tid & 3) == 0)                                          \
                    __builtin_nontemporal_store(O3, r_ + 21 + (tid >> 2));   \
                __builtin_nontemporal_store(O4, r_ + 85 + tid);              \
            }                                                                \
        } while (0)
        SIG_STORE_ROW(0, o1_0, o2_0, o3_0, o4_0);
        SIG_STORE_ROW(1, o1_1, o2_1, o3_1, o4_1);
        SIG_STORE_ROW(2, o1_2, o2_2, o3_2, o4_2);
        SIG_STORE_ROW(3, o1_3, o2_3, o3_3, o4_3);
#undef SIG_STORE_ROW
    }
}

extern "C" void kernel_launch(void* const* d_in, const int* in_sizes, int n_in,
                              void* d_out, int out_size, void* d_ws, size_t ws_size,
                              hipStream_t stream) {
    const float* x = (const float*)d_in[0];   // (32, 512, 4) f32
    float* out = (float*)d_out;               // (32, 512, 341) f32
    float* Lsig = (float*)d_ws;               // 512 * 344 floats

    sigA<<<SIG_B * SIG_C, 256, 0, stream>>>(x, Lsig);
    sigC<<<SIG_B * SIG_C, 256, 0, stream>>>(x, Lsig, out);
}